// Round 3
// baseline (145.806 us; speedup 1.0000x reference)
//
#include <hip/hip_runtime.h>
#include <hip/hip_bf16.h>

// Problem constants (fixed by setup_inputs): coords (2, 4096, 3) float32, num_k = 30.
// Outputs: one flat FLOAT32 buffer, reference return order.
// R3: phase-1 scan with v_med3 value updates + inline-const t tracking (full
// unroll) + dual accumulator sets (halved carried chain, 2x ILP) merged by an
// exact lex merge with exact 3rd-smallest for the hazard check. Frame drops
// acosf/sin/cos via algebraic identities. Phase-2 empty check via readlane.
constexpr int B = 2;
constexpr int N = 4096;
constexpr int K = 30;
constexpr int ROWS_PER_BLK = 4;

constexpr size_t OFF_POS = 0;                                   // B*N*K*16
constexpr size_t OFF_AD  = OFF_POS + (size_t)B * N * K * 16;    // B*N*3
constexpr size_t OFF_O   = OFF_AD  + (size_t)B * N * 3;         // B*N*K*3
constexpr size_t OFF_GS  = OFF_O   + (size_t)B * N * K * 3;     // B*N*K*15
constexpr size_t OFF_DN  = OFF_GS  + (size_t)B * N * K * 15;    // B*N*K
constexpr size_t OFF_E   = OFF_DN  + (size_t)B * N * K;         // B*N*K

constexpr float BIGD = 1e30f;               // d/s identity (real d < 300, s < 9e4)
constexpr unsigned int BIGJ = 0xFFFFFFFFu;  // j identity for u32 min

struct F3 { float x, y, z; };               // 12B -> global_load_dwordx3

typedef float v2f __attribute__((ext_vector_type(2)));

template <bool ISBF16>
__device__ __forceinline__ float ldx(const void* __restrict__ X, int idx) {
  if constexpr (ISBF16) {
    return __bfloat162float(((const __hip_bfloat16*)X)[idx]);
  } else {
    return ((const float*)X)[idx];
  }
}

// Selection exactness: np-exact f32 ops, no FMA. s (squared+eps) must be
// bit-identical between phase-1 scan, fallback rescan, and phase-2 refill.
template <bool ISBF16>
__device__ __forceinline__ float dist_core(float px, float py, float pz,
                                           float xi, float yi, float zi) {
#pragma clang fp contract(off)
  const float dx = px - xi;
  const float dy = py - yi;
  const float dz = pz - zi;
  return sqrtf(((dx * dx + dy * dy) + dz * dz) + 1e-6f);
}

template <bool ISBF16>
__device__ __forceinline__ float distf(const void* __restrict__ Xb, int j,
                                       float xi, float yi, float zi) {
  float px, py, pz;
  if constexpr (ISBF16) {
    px = ldx<true>(Xb, j * 3 + 0);
    py = ldx<true>(Xb, j * 3 + 1);
    pz = ldx<true>(Xb, j * 3 + 2);
  } else {
    const F3 p = ((const F3*)Xb)[j];   // one dwordx3 load
    px = p.x; py = p.y; pz = p.z;
  }
  return dist_core<ISBF16>(px, py, pz, xi, yi, zi);
}

// ---- DPP 64-lane min reductions, full-rate f32/u32 ops -------------------
template <int CTRL>
__device__ __forceinline__ float dpp_min_f32(float v) {
  const int mv = __builtin_amdgcn_update_dpp(__float_as_int(BIGD), __float_as_int(v),
                                             CTRL, 0xF, 0xF, false);
  return fminf(__int_as_float(mv), v);
}
template <int CTRL>
__device__ __forceinline__ unsigned int dpp_min_u32(unsigned int v) {
  const unsigned int mv = (unsigned int)__builtin_amdgcn_update_dpp(
      (int)BIGJ, (int)v, CTRL, 0xF, 0xF, false);
  return mv < v ? mv : v;
}
__device__ __forceinline__ float wave_min_f32_bcast(float v) {
  v = dpp_min_f32<0x111>(v);   // row_shr:1
  v = dpp_min_f32<0x112>(v);   // row_shr:2
  v = dpp_min_f32<0x114>(v);   // row_shr:4
  v = dpp_min_f32<0x118>(v);   // row_shr:8
  v = dpp_min_f32<0x142>(v);   // row_bcast:15
  v = dpp_min_f32<0x143>(v);   // row_bcast:31 -> lane 63 = global min
  return __int_as_float(__builtin_amdgcn_readlane(__float_as_int(v), 63));
}
__device__ __forceinline__ unsigned int wave_min_u32_bcast(unsigned int v) {
  v = dpp_min_u32<0x111>(v);
  v = dpp_min_u32<0x112>(v);
  v = dpp_min_u32<0x114>(v);
  v = dpp_min_u32<0x118>(v);
  v = dpp_min_u32<0x142>(v);
  v = dpp_min_u32<0x143>(v);
  return (unsigned int)__builtin_amdgcn_readlane((int)v, 63);
}

// Lex (d, j) argmin over heads, wave-uniform result. Matches top_k stable order.
__device__ __forceinline__ void lex_argmin(float d0, int j0,
                                           float& dmin, unsigned int& jmin) {
  dmin = wave_min_f32_bcast(d0);
  const unsigned long long tie = __ballot(d0 == dmin);
  if (__popcll(tie) == 1) {                 // wave-uniform branch
    const int wl = __ffsll((unsigned long long)tie) - 1;
    jmin = (unsigned int)__builtin_amdgcn_readlane(j0, wl);
  } else {
    const unsigned int jc = (d0 == dmin) ? (unsigned int)j0 : BIGJ;
    jmin = wave_min_u32_bcast(jc);
  }
}

// range-reduce to |r| <= pi, then native sin/cos (safe domain for v_sin/v_cos)
__device__ __forceinline__ float red2pi(float x) {
  return x - 6.28318530718f * rintf(x * 0.15915494309f);
}

// Feature-path normalize: native sqrt/rcp (1 ulp). inv is a SHARED positive
// scale across x,y,z -> downstream directions, signs, and dot-sign tests are
// unaffected; magnitude off by ~2 ulp (2% output threshold).
__device__ __forceinline__ void norm3(float& x, float& y, float& z) {
  float n = __builtin_amdgcn_sqrtf((x * x + y * y) + z * z);
  n = fmaxf(n, 1e-12f);
  const float inv = __builtin_amdgcn_rcpf(n);
  x *= inv; y *= inv; z *= inv;
}

__device__ __forceinline__ void cross3(float ax, float ay, float az,
                                       float bx, float by, float bz,
                                       float& cx, float& cy, float& cz) {
  cx = ay * bz - az * by;
  cy = az * bx - ax * bz;
  cz = ax * by - ay * bx;
}

// Sorted top-2 insert by full key (fallback path only).
__device__ __forceinline__ void ins2(float d, int j,
                                     float& d0, float& d1, int& j0, int& j1) {
  const bool lt1 = d < d1;
  const float td = lt1 ? d : d1;
  const int   tj = lt1 ? j : j1;
  const bool lt0 = td < d0;
  d1 = lt0 ? d0 : td;  j1 = lt0 ? j0 : tj;
  d0 = lt0 ? td : d0;  j0 = lt0 ? tj : j0;
}

// One scan step for one accumulator set. T is an unroll-time constant (<= 63
// -> inline constant in v_cndmask). Value updates: 2x v_med3 + v_min (exact
// selection ops, no rounding); index updates: 3 cndmask off 2 cmps.
// Maintains exact sorted top-3 VALUES (s0<=s1<=s2) and top-2 t-indices,
// j-stable under strict < (t ascends during the scan).
__device__ __forceinline__ void step_med3(float s, int T,
                                          float& s0, float& s1, float& s2,
                                          int& t0, int& t1) {
  const bool c0 = s < s0;
  const bool c1 = s < s1;
  const float n2 = __builtin_amdgcn_fmed3f(s, s1, s2);  // uses OLD s1
  const float n1 = __builtin_amdgcn_fmed3f(s, s0, s1);  // uses OLD s0,s1
  const float n0 = fminf(s, s0);
  t1 = c0 ? t0 : (c1 ? T : t1);                          // uses OLD t0
  t0 = c0 ? T : t0;
  s2 = n2; s1 = n1; s0 = n0;
}

template <bool ISBF16>
__device__ __forceinline__ void body(const void* __restrict__ Xb,
                                     float* __restrict__ out,
                                     int b, int i, int lane) {
  const float xi = ldx<ISBF16>(Xb, i * 3 + 0);
  const float yi = ldx<ISBF16>(Xb, i * 3 + 1);
  const float zi = ldx<ISBF16>(Xb, i * 3 + 2);

  // ---- Phase 1: lane l owns column {j : j % 64 == l}. Select by squared
  // distance s (no sqrt in loop). Dual independent sets (t in [0,32),[32,64))
  // for 2x ILP and half the carried chain; exact lex merge afterward.
  float d0, d1;
  int   j0, j1;
  bool  hazard;
  {
    float s0m, s1m, s2m;
    int   t0m, t1m;
    if constexpr (!ISBF16) {
      const F3* __restrict__ P = ((const F3*)Xb) + lane;
      const v2f xyi = {xi, yi};
      float sA0 = BIGD, sA1 = BIGD, sA2 = BIGD;
      float sB0 = BIGD, sB1 = BIGD, sB2 = BIGD;
      int tA0 = 0, tA1 = 0, tB0 = 32, tB1 = 32;
#pragma unroll
      for (int tt = 0; tt < 32; ++tt) {      // FULL unroll: tt is a literal
        {
          const F3 p = P[tt * 64];
          float s;
          {
#pragma clang fp contract(off)
            const v2f pxy = {p.x, p.y};      // consecutive VGPRs from dwordx3
            const v2f a = pxy - xyi;
            const v2f m = a * a;
            const float dz = p.z - zi;
            s = ((m.x + m.y) + dz * dz) + 1e-6f;
          }
          step_med3(s, tt, sA0, sA1, sA2, tA0, tA1);
        }
        {
          const F3 p = P[(tt + 32) * 64];
          float s;
          {
#pragma clang fp contract(off)
            const v2f pxy = {p.x, p.y};
            const v2f a = pxy - xyi;
            const v2f m = a * a;
            const float dz = p.z - zi;
            s = ((m.x + m.y) + dz * dz) + 1e-6f;
          }
          step_med3(s, tt + 32, sB0, sB1, sB2, tB0, tB1);
        }
      }
      // ---- Exact lex merge of the two sorted sets (same lane => j order is
      // t order; all A t's < all B t's matters only through explicit t cmp).
      const bool bfirst = sB0 < sA0;          // strict: tie -> A (smaller t)
      s0m = bfirst ? sB0 : sA0;
      t0m = bfirst ? tB0 : tA0;
      const float sx = bfirst ? sA0 : sB0;    // loser of firsts (= max value)
      const int   tx = bfirst ? tA0 : tB0;
      const bool bsec = sB1 < sA1;
      const float sy = bsec ? sB1 : sA1;      // winner of seconds (= min value)
      const int   ty = bsec ? tB1 : tA1;
      const bool pickY = (sy < sx) || (sy == sx && ty < tx);
      s1m = pickY ? sy : sx;
      t1m = pickY ? ty : tx;
      // exact 3rd-smallest VALUE of the union (hazard check input):
      const float xm = fmaxf(sA0, sB0);
      const float ym = fminf(sA1, sB1);
      const float t3 = fmaxf(xm, ym);
      const float z  = fminf(fmaxf(sA1, sB1), fminf(sA2, sB2));
      s2m = fminf(t3, z);
      j0 = (t0m << 6) | lane;
      j1 = (t1m << 6) | lane;
    } else {
      // bf16 hedge path: single set, med3 values + direct j tracking.
      float s0 = BIGD, s1 = BIGD, s2 = BIGD;
      int jj0 = 0x7FFFFFFF, jj1 = 0x7FFFFFFF;
#pragma unroll 8
      for (int t = 0; t < 64; ++t) {
        const int j = t * 64 + lane;
        const float px = ldx<true>(Xb, j * 3 + 0);
        const float py = ldx<true>(Xb, j * 3 + 1);
        const float pz = ldx<true>(Xb, j * 3 + 2);
        float s;
        {
#pragma clang fp contract(off)
          const float dx = px - xi;
          const float dy = py - yi;
          const float dz = pz - zi;
          s = ((dx * dx + dy * dy) + dz * dz) + 1e-6f;
        }
        const bool c0 = s < s0;
        const bool c1 = s < s1;
        const float n2 = __builtin_amdgcn_fmed3f(s, s1, s2);
        const float n1 = __builtin_amdgcn_fmed3f(s, s0, s1);
        const float n0 = fminf(s, s0);
        jj1 = c0 ? jj0 : (c1 ? j : jj1);
        jj0 = c0 ? j : jj0;
        s2 = n2; s1 = n1; s0 = n0;
      }
      s0m = s0; s1m = s1; s2m = s2; j0 = jj0; j1 = jj1;
      t0m = 0; t1m = 0; (void)t0m; (void)t1m;
    }

    // ---- Convert to exact d (precise sqrt, bit-identical to distf). ----
    // d = round(sqrt(s)) monotone in s. If d1 < d2 := sqrt(s2m), every evicted
    // element is strictly d-greater than both kept -> cache is EXACTLY the
    // column top-2 by (d, j). On d0==d1 restore j-ascending order. If d1==d2
    // a hidden d-tie with smaller j may exist -> exact d-keyed rescan.
    d0 = sqrtf(s0m); d1 = sqrtf(s1m);
    const float d2v = sqrtf(s2m);
    if (d0 == d1 && j0 > j1) { const int t = j0; j0 = j1; j1 = t; }
    hazard = (__ballot(d1 == d2v) != 0ull);   // wave-uniform, ~never taken
  }
  if (hazard) {
    d0 = BIGD; d1 = BIGD; j0 = 0x7FFFFFFF; j1 = 0x7FFFFFFF;
    for (int t = 0; t < 64; ++t) {
      const int j = t * 64 + lane;
      const float d = distf<ISBF16>(Xb, j, xi, yi, zi);
      ins2(d, j, d0, d1, j0, j1);
    }
  }

  // ---- Phase 2: 30 pops. lex_argmin over heads; winner lane shifts its
  // cache; if it emptied, cooperatively recompute its column (bit-identical
  // distf) with consumed-mask exclusion and refill (~0.65 refills/row).
  unsigned long long exm = 0;   // consumed t's within this lane's own column
  int   sjv = 0;                // lane k (<K): neighbor k's index j
  float sdv = 0.0f;             // lane k (<K): neighbor k's distance d
  for (int k = 0; k < K; ++k) {
    float dmin; unsigned int jmin;
    lex_argmin(d0, j0, dmin, jmin);
    if (lane == k) { sjv = (int)jmin; sdv = dmin; }

    const int w  = (int)(jmin & 63u);   // winning column (wave-uniform)
    const int tw = (int)(jmin >> 6);
    if (lane == w) {            // pop head, mark consumed
      exm |= (1ull << tw);
      d0 = d1; j0 = j1;
      d1 = BIGD; j1 = 0x7FFFFFFF;
    }
    // only the just-popped lane can be empty: scalar check via readlane
    if (__builtin_amdgcn_readlane(__float_as_int(d0), w) == __float_as_int(BIGD)) {
      const unsigned int mlo = (unsigned int)__builtin_amdgcn_readlane((int)(unsigned int)(exm & 0xFFFFFFFFull), w);
      const unsigned int mhi = (unsigned int)__builtin_amdgcn_readlane((int)(unsigned int)(exm >> 32), w);
      const unsigned long long m = ((unsigned long long)mhi << 32) | mlo;
      const int j2 = (lane << 6) | w;      // lane t recomputes column w entry t
      const float d2 = distf<ISBF16>(Xb, j2, xi, yi, zi);
      const float dc = ((m >> lane) & 1ull) ? BIGD : d2;
      float dmin2; unsigned int jmin2;
      lex_argmin(dc, j2, dmin2, jmin2);
      if (lane == w) { d0 = dmin2; j0 = (int)jmin2; }
    }
  }

  // ---- Row-uniform AD features and frame O3 (all lanes redundantly). ----
  // AD via identities: cos(acos x)=x, sin(acos x)=sqrt(1-x^2) (A in [0,pi]),
  // sin(sg*acos x)=sg*sqrt(1-x^2) -- no acos/sin/cos chains.
  float ad0 = 0.f, ad1 = 0.f, ad2 = 0.f;
  float o00 = 0.f, o01 = 0.f, o02 = 0.f;
  float o10 = 0.f, o11 = 0.f, o12 = 0.f;
  float o20 = 0.f, o21 = 0.f, o22 = 0.f;
  if (i >= 1 && i <= N - 3) {
    const float ax = ldx<ISBF16>(Xb, (i - 1) * 3 + 0), ay = ldx<ISBF16>(Xb, (i - 1) * 3 + 1), az = ldx<ISBF16>(Xb, (i - 1) * 3 + 2);
    const float cx = ldx<ISBF16>(Xb, (i + 1) * 3 + 0), cy = ldx<ISBF16>(Xb, (i + 1) * 3 + 1), cz = ldx<ISBF16>(Xb, (i + 1) * 3 + 2);
    const float ex = ldx<ISBF16>(Xb, (i + 2) * 3 + 0), ey = ldx<ISBF16>(Xb, (i + 2) * 3 + 1), ez = ldx<ISBF16>(Xb, (i + 2) * 3 + 2);
    float u2x = xi - ax, u2y = yi - ay, u2z = zi - az; norm3(u2x, u2y, u2z);  // U[i-1]
    float u1x = cx - xi, u1y = cy - yi, u1z = cz - zi; norm3(u1x, u1y, u1z);  // U[i]
    float u0x = ex - cx, u0y = ey - cy, u0z = ez - cz; norm3(u0x, u0y, u0z);  // U[i+1]
    float n2x, n2y, n2z; cross3(u2x, u2y, u2z, u1x, u1y, u1z, n2x, n2y, n2z); norm3(n2x, n2y, n2z);
    float n1x, n1y, n1z; cross3(u1x, u1y, u1z, u0x, u0y, u0z, n1x, n1y, n1z); norm3(n1x, n1y, n1z);
    const float dotu = (u1x * u0x + u1y * u0y) + u1z * u0z;
    const float cosA = fminf(fmaxf(-dotu, -1.0f + 1e-6f), 1.0f - 1e-6f);
    const float sinA = __builtin_amdgcn_sqrtf(fmaxf(1.0f - cosA * cosA, 0.0f));
    const float dotn = (n2x * n1x + n2y * n1y) + n2z * n1z;
    const float cosD = fminf(fmaxf(dotn, -1.0f + 1e-6f), 1.0f - 1e-6f);
    const float sinDm = __builtin_amdgcn_sqrtf(fmaxf(1.0f - cosD * cosD, 0.0f));
    const float du2n1 = (u2x * n1x + u2y * n1y) + u2z * n1z;
    const float sg = (du2n1 > 0.f) ? 1.f : ((du2n1 < 0.f) ? -1.f : 0.f);
    ad0 = cosA; ad1 = sinA * cosD; ad2 = sinA * (sg * sinDm);
    float o1x = u2x - u1x, o1y = u2y - u1y, o1z = u2z - u1z; norm3(o1x, o1y, o1z);
    o00 = o1x; o01 = o1y; o02 = o1z;
    o10 = n2x; o11 = n2y; o12 = n2z;
    cross3(o1x, o1y, o1z, n2x, n2y, n2z, o20, o21, o22);
  }

  const int row = b * N + i;

  // ---- Phase 3a: pos_emb, all 64 lanes over 480 contiguous values. ----
  // p = idx & 15 is loop-invariant (64 % 16 == 0): hoist freq and cos/sin pick.
  {
    const size_t base = OFF_POS + (size_t)row * (K * 16);
    const int p = lane & 15;
    const float fr = __expf((float)((p & 7) * 2) * -0.57564627f);
    const bool is_cos = (p < 8);
#pragma unroll
    for (int it = 0; it < 8; ++it) {
      const int idx = it * 64 + lane;
      const int k = (idx >> 4) < K ? (idx >> 4) : (K - 1);
      const int jk = __shfl(sjv, k, 64);     // uniform-active shfl
      const float df = (float)(jk - i);
      const float r = red2pi(df * fr);
      const float v = is_cos ? __cosf(r) : __sinf(r);
      if (idx < K * 16) out[base + idx] = v;
    }
  }

  // ---- Phase 3b: gs_d, all 64 lanes over 450 contiguous values. ----
  {
    const size_t base = OFF_GS + (size_t)row * (K * 15);
#pragma unroll
    for (int it = 0; it < 8; ++it) {
      const int idx = it * 64 + lane;
      const int kq = idx / 15;
      const int k = kq < K ? kq : (K - 1);
      const int m = idx - kq * 15;
      const float d = __shfl(sdv, k, 64);    // uniform-active shfl
      const float mu = (float)(m * (20.0 / 14.0));
      const float q = (d - mu) * 0.75f;
      const float v = __expf(-(q * q));
      if (idx < K * 15) out[base + idx] = v;
    }
  }

  // ---- Phase 3c: E_idx, D_neighbors, O_features on lanes < K; AD on 30..32. ----
  if (lane < K) {
    const size_t rowk = (size_t)row * K + lane;
    const int   j = sjv;
    out[OFF_E  + rowk] = (float)j;
    out[OFF_DN + rowk] = sdv;

    // O_features: normalize(O3 @ (X[j] - X[i])), eps 1e-12; shared rcp scale
    float px, py, pz;
    if constexpr (ISBF16) {
      px = ldx<true>(Xb, j * 3 + 0);
      py = ldx<true>(Xb, j * 3 + 1);
      pz = ldx<true>(Xb, j * 3 + 2);
    } else {
      const F3 p = ((const F3*)Xb)[j];
      px = p.x; py = p.y; pz = p.z;
    }
    const float gx = px - xi, gy = py - yi, gz = pz - zi;
    const float v0 = (o00 * gx + o01 * gy) + o02 * gz;
    const float v1 = (o10 * gx + o11 * gy) + o12 * gz;
    const float v2 = (o20 * gx + o21 * gy) + o22 * gz;
    const float nn = fmaxf(__builtin_amdgcn_sqrtf((v0 * v0 + v1 * v1) + v2 * v2), 1e-12f);
    const float inv = __builtin_amdgcn_rcpf(nn);
    out[OFF_O + rowk * 3 + 0] = v0 * inv;
    out[OFF_O + rowk * 3 + 1] = v1 * inv;
    out[OFF_O + rowk * 3 + 2] = v2 * inv;
  } else if (lane < K + 3) {
    const int c = lane - K;
    const float v = (c == 0) ? ad0 : (c == 1) ? ad1 : ad2;
    out[OFF_AD + (size_t)row * 3 + c] = v;
  }
}

__global__ __launch_bounds__(64 * ROWS_PER_BLK)
void protein_feat_kernel(const void* __restrict__ X,
                         float* __restrict__ out) {
  const int lane = threadIdx.x & 63;
  const int wv   = threadIdx.x >> 6;               // wave id within WG
  const int row  = blockIdx.x * ROWS_PER_BLK + wv; // 0..B*N-1 (independent per wave)
  const int b    = row >> 12;
  const int i    = row & (N - 1);

  // ---- Input-dtype sniff (hedge): even-indexed uint16s are sane bf16 coords
  // iff the buffer is truly bf16; for float32 they are mantissa noise.
  const unsigned short h = ((const unsigned short*)X)[2 * lane];
  const int e = (h >> 7) & 0xFF;
  const bool sane = ((h & 0x7FFF) == 0) || (e >= 115 && e <= 134);
  const unsigned long long bal = __ballot(sane);
  const bool isbf16 = __popcll(bal) >= 40;

  if (isbf16) {
    const void* Xb = (const void*)((const __hip_bfloat16*)X + (size_t)b * N * 3);
    body<true>(Xb, out, b, i, lane);
  } else {
    const void* Xb = (const void*)((const float*)X + (size_t)b * N * 3);
    body<false>(Xb, out, b, i, lane);
  }
}

extern "C" void kernel_launch(void* const* d_in, const int* in_sizes, int n_in,
                              void* d_out, int out_size, void* d_ws, size_t ws_size,
                              hipStream_t stream) {
  const void* X = d_in[0];
  float* out = (float*)d_out;
  (void)in_sizes; (void)n_in; (void)d_ws; (void)ws_size; (void)out_size;
  protein_feat_kernel<<<dim3(B * N / ROWS_PER_BLK), dim3(64 * ROWS_PER_BLK), 0, stream>>>(X, out);
}

// Round 4
// 106.929 us; speedup vs baseline: 1.3636x; 1.3636x over previous
//
#include <hip/hip_runtime.h>
#include <hip/hip_bf16.h>

// Problem constants (fixed by setup_inputs): coords (2, 4096, 3) float32, num_k = 30.
// Outputs: one flat FLOAT32 buffer, reference return order.
// R4 = R2 structure (unroll 8, single accumulator set, 32 VGPR / 50% occ —
// R3's full-unroll dual-set hit 76 VGPR and went latency-bound) + register-
// neutral shavings: med3 value updates, eps-free scan key (monotone; exact
// via post-loop eps fold + hazard rescan), identity-based frame trig,
// readlane phase-2 empty check.
constexpr int B = 2;
constexpr int N = 4096;
constexpr int K = 30;
constexpr int ROWS_PER_BLK = 4;

constexpr size_t OFF_POS = 0;                                   // B*N*K*16
constexpr size_t OFF_AD  = OFF_POS + (size_t)B * N * K * 16;    // B*N*3
constexpr size_t OFF_O   = OFF_AD  + (size_t)B * N * 3;         // B*N*K*3
constexpr size_t OFF_GS  = OFF_O   + (size_t)B * N * K * 3;     // B*N*K*15
constexpr size_t OFF_DN  = OFF_GS  + (size_t)B * N * K * 15;    // B*N*K
constexpr size_t OFF_E   = OFF_DN  + (size_t)B * N * K;         // B*N*K

constexpr float BIGD = 1e30f;               // d/s identity (real d < 300, s < 9e4)
constexpr unsigned int BIGJ = 0xFFFFFFFFu;  // j identity for u32 min

struct F3 { float x, y, z; };               // 12B -> global_load_dwordx3

typedef float v2f __attribute__((ext_vector_type(2)));

template <bool ISBF16>
__device__ __forceinline__ float ldx(const void* __restrict__ X, int idx) {
  if constexpr (ISBF16) {
    return __bfloat162float(((const __hip_bfloat16*)X)[idx]);
  } else {
    return ((const float*)X)[idx];
  }
}

// Selection exactness: np-exact f32 ops, no FMA. The squared sum must use the
// SAME association everywhere: ((dx*dx + dy*dy) + dz*dz), then + 1e-6f.
template <bool ISBF16>
__device__ __forceinline__ float dist_core(float px, float py, float pz,
                                           float xi, float yi, float zi) {
#pragma clang fp contract(off)
  const float dx = px - xi;
  const float dy = py - yi;
  const float dz = pz - zi;
  return sqrtf(((dx * dx + dy * dy) + dz * dz) + 1e-6f);
}

template <bool ISBF16>
__device__ __forceinline__ float distf(const void* __restrict__ Xb, int j,
                                       float xi, float yi, float zi) {
  float px, py, pz;
  if constexpr (ISBF16) {
    px = ldx<true>(Xb, j * 3 + 0);
    py = ldx<true>(Xb, j * 3 + 1);
    pz = ldx<true>(Xb, j * 3 + 2);
  } else {
    const F3 p = ((const F3*)Xb)[j];   // one dwordx3 load
    px = p.x; py = p.y; pz = p.z;
  }
  return dist_core<ISBF16>(px, py, pz, xi, yi, zi);
}

// ---- DPP 64-lane min reductions, full-rate f32/u32 ops -------------------
template <int CTRL>
__device__ __forceinline__ float dpp_min_f32(float v) {
  const int mv = __builtin_amdgcn_update_dpp(__float_as_int(BIGD), __float_as_int(v),
                                             CTRL, 0xF, 0xF, false);
  return fminf(__int_as_float(mv), v);
}
template <int CTRL>
__device__ __forceinline__ unsigned int dpp_min_u32(unsigned int v) {
  const unsigned int mv = (unsigned int)__builtin_amdgcn_update_dpp(
      (int)BIGJ, (int)v, CTRL, 0xF, 0xF, false);
  return mv < v ? mv : v;
}
__device__ __forceinline__ float wave_min_f32_bcast(float v) {
  v = dpp_min_f32<0x111>(v);   // row_shr:1
  v = dpp_min_f32<0x112>(v);   // row_shr:2
  v = dpp_min_f32<0x114>(v);   // row_shr:4
  v = dpp_min_f32<0x118>(v);   // row_shr:8
  v = dpp_min_f32<0x142>(v);   // row_bcast:15
  v = dpp_min_f32<0x143>(v);   // row_bcast:31 -> lane 63 = global min
  return __int_as_float(__builtin_amdgcn_readlane(__float_as_int(v), 63));
}
__device__ __forceinline__ unsigned int wave_min_u32_bcast(unsigned int v) {
  v = dpp_min_u32<0x111>(v);
  v = dpp_min_u32<0x112>(v);
  v = dpp_min_u32<0x114>(v);
  v = dpp_min_u32<0x118>(v);
  v = dpp_min_u32<0x142>(v);
  v = dpp_min_u32<0x143>(v);
  return (unsigned int)__builtin_amdgcn_readlane((int)v, 63);
}

// Lex (d, j) argmin over heads, wave-uniform result. Matches top_k stable order.
__device__ __forceinline__ void lex_argmin(float d0, int j0,
                                           float& dmin, unsigned int& jmin) {
  dmin = wave_min_f32_bcast(d0);
  const unsigned long long tie = __ballot(d0 == dmin);
  if (__popcll(tie) == 1) {                 // wave-uniform branch
    const int wl = __ffsll((unsigned long long)tie) - 1;
    jmin = (unsigned int)__builtin_amdgcn_readlane(j0, wl);
  } else {
    const unsigned int jc = (d0 == dmin) ? (unsigned int)j0 : BIGJ;
    jmin = wave_min_u32_bcast(jc);
  }
}

// range-reduce to |r| <= pi, then native sin/cos (safe domain for v_sin/v_cos)
__device__ __forceinline__ float red2pi(float x) {
  return x - 6.28318530718f * rintf(x * 0.15915494309f);
}

// Feature-path normalize: native sqrt/rcp (1 ulp). inv is a SHARED positive
// scale across x,y,z -> downstream directions, signs, and dot-sign tests are
// unaffected; magnitude off by ~2 ulp (2% output threshold).
__device__ __forceinline__ void norm3(float& x, float& y, float& z) {
  float n = __builtin_amdgcn_sqrtf((x * x + y * y) + z * z);
  n = fmaxf(n, 1e-12f);
  const float inv = __builtin_amdgcn_rcpf(n);
  x *= inv; y *= inv; z *= inv;
}

__device__ __forceinline__ void cross3(float ax, float ay, float az,
                                       float bx, float by, float bz,
                                       float& cx, float& cy, float& cz) {
  cx = ay * bz - az * by;
  cy = az * bx - ax * bz;
  cz = ax * by - ay * bx;
}

// Sorted top-2 insert by full key (fallback rescan path only).
__device__ __forceinline__ void ins2(float d, int j,
                                     float& d0, float& d1, int& j0, int& j1) {
  const bool lt1 = d < d1;
  const float td = lt1 ? d : d1;
  const int   tj = lt1 ? j : j1;
  const bool lt0 = td < d0;
  d1 = lt0 ? d0 : td;  j1 = lt0 ? j0 : tj;
  d0 = lt0 ? td : d0;  j0 = lt0 ? tj : j0;
}

template <bool ISBF16>
__device__ __forceinline__ void body(const void* __restrict__ Xb,
                                     float* __restrict__ out,
                                     int b, int i, int lane) {
  const float xi = ldx<ISBF16>(Xb, i * 3 + 0);
  const float yi = ldx<ISBF16>(Xb, i * 3 + 1);
  const float zi = ldx<ISBF16>(Xb, i * 3 + 2);

  // ---- Phase 1: lane l owns column {j : j % 64 == l}. Select by RAW squared
  // sum ss (no sqrt, no +eps in the loop). Value updates via v_med3 (exact
  // selection ops): s1=med3(ss,s0,s1), s2v=med3(ss,s1_old,s2v), s0=min.
  // Index updates: 3 cndmask off 2 cmps; strict < is j-stable (j ascends).
  float s0 = BIGD, s1 = BIGD, s2v = BIGD;
  int   j0 = 0x7FFFFFFF, j1 = 0x7FFFFFFF;
  if constexpr (!ISBF16) {
    const F3* __restrict__ P = ((const F3*)Xb) + lane;  // pointer-strided
    const v2f xyi = {xi, yi};
#pragma unroll 8
    for (int t = 0; t < 64; ++t) {
      const F3 p = P[t * 64];
      const int j = t * 64 + lane;
      float ss;
      {
#pragma clang fp contract(off)
        const v2f pxy = {p.x, p.y};          // consecutive VGPRs from dwordx3
        const v2f a = pxy - xyi;             // v_pk_add_f32 (sub)
        const v2f m = a * a;                 // v_pk_mul_f32
        const float dz = p.z - zi;
        ss = (m.x + m.y) + dz * dz;          // same assoc as dist_core (pre-eps)
      }
      const bool c0 = ss < s0;
      const bool c1 = ss < s1;
      const float n1 = __builtin_amdgcn_fmed3f(ss, s0, s1);   // OLD s0,s1
      s2v = __builtin_amdgcn_fmed3f(ss, s1, s2v);             // OLD s1
      s0 = fminf(ss, s0);
      j1 = c0 ? j0 : (c1 ? j : j1);                           // OLD j0
      j0 = c0 ? j : j0;
      s1 = n1;
    }
  } else {
#pragma unroll 8
    for (int t = 0; t < 64; ++t) {
      const int j = t * 64 + lane;
      const float px = ldx<true>(Xb, j * 3 + 0);
      const float py = ldx<true>(Xb, j * 3 + 1);
      const float pz = ldx<true>(Xb, j * 3 + 2);
      float ss;
      {
#pragma clang fp contract(off)
        const float dx = px - xi;
        const float dy = py - yi;
        const float dz = pz - zi;
        ss = (dx * dx + dy * dy) + dz * dz;
      }
      const bool c0 = ss < s0;
      const bool c1 = ss < s1;
      const float n1 = __builtin_amdgcn_fmed3f(ss, s0, s1);
      s2v = __builtin_amdgcn_fmed3f(ss, s1, s2v);
      s0 = fminf(ss, s0);
      j1 = c0 ? j0 : (c1 ? j : j1);
      j0 = c0 ? j : j0;
      s1 = n1;
    }
  }

  // ---- Convert to exact d: fold +eps then precise sqrt — bit-identical to
  // distf's final ops. Exactness: d(x)=sqrt((x+eps) rounded) is monotone
  // non-decreasing in x, so {top-2 by ss} == {top-2 by d} as a SET.
  //  * In-cache order: ss0<=ss1 -> d0<=d1; on d0==d1 restore j-ascending.
  //  * If d1 == d2v: an evicted element (ss >= s2v -> d >= d2v) may d-tie the
  //    kept 2nd with smaller j -> exact d-keyed rescan (probability ~0).
  float d0 = sqrtf(s0 + 1e-6f), d1 = sqrtf(s1 + 1e-6f);
  const float d2v = sqrtf(s2v + 1e-6f);
  if (d0 == d1 && j0 > j1) { const int t = j0; j0 = j1; j1 = t; }
  const bool hazard = (__ballot(d1 == d2v) != 0ull);   // wave-uniform
  if (hazard) {
    d0 = BIGD; d1 = BIGD; j0 = 0x7FFFFFFF; j1 = 0x7FFFFFFF;
    for (int t = 0; t < 64; ++t) {
      const int j = t * 64 + lane;
      const float d = distf<ISBF16>(Xb, j, xi, yi, zi);
      ins2(d, j, d0, d1, j0, j1);
    }
  }

  // ---- Phase 2: 30 pops. lex_argmin over heads; winner lane shifts its
  // cache; if it emptied, cooperatively recompute its column (bit-identical
  // distf) with consumed-mask exclusion and refill (~0.65 refills/row).
  unsigned long long exm = 0;   // consumed t's within this lane's own column
  int   sjv = 0;                // lane k (<K): neighbor k's index j
  float sdv = 0.0f;             // lane k (<K): neighbor k's distance d
  for (int k = 0; k < K; ++k) {
    float dmin; unsigned int jmin;
    lex_argmin(d0, j0, dmin, jmin);
    if (lane == k) { sjv = (int)jmin; sdv = dmin; }

    const int w  = (int)(jmin & 63u);   // winning column (wave-uniform)
    const int tw = (int)(jmin >> 6);
    if (lane == w) {            // pop head, mark consumed
      exm |= (1ull << tw);
      d0 = d1; j0 = j1;
      d1 = BIGD; j1 = 0x7FFFFFFF;
    }
    // only the just-popped lane can be empty: scalar check via readlane
    if (__builtin_amdgcn_readlane(__float_as_int(d0), w) == __float_as_int(BIGD)) {
      const unsigned int mlo = (unsigned int)__builtin_amdgcn_readlane((int)(unsigned int)(exm & 0xFFFFFFFFull), w);
      const unsigned int mhi = (unsigned int)__builtin_amdgcn_readlane((int)(unsigned int)(exm >> 32), w);
      const unsigned long long m = ((unsigned long long)mhi << 32) | mlo;
      const int j2 = (lane << 6) | w;      // lane t recomputes column w entry t
      const float d2 = distf<ISBF16>(Xb, j2, xi, yi, zi);
      const float dc = ((m >> lane) & 1ull) ? BIGD : d2;
      float dmin2; unsigned int jmin2;
      lex_argmin(dc, j2, dmin2, jmin2);
      if (lane == w) { d0 = dmin2; j0 = (int)jmin2; }
    }
  }

  // ---- Row-uniform AD features and frame O3 (all lanes redundantly). ----
  // Identities: cos(acos x)=x, sin(acos x)=sqrt(1-x^2) (A in [0,pi]),
  // sin(sg*acos x)=sg*sqrt(1-x^2) -- no acos/sin/cos chains (R3-validated).
  float ad0 = 0.f, ad1 = 0.f, ad2 = 0.f;
  float o00 = 0.f, o01 = 0.f, o02 = 0.f;
  float o10 = 0.f, o11 = 0.f, o12 = 0.f;
  float o20 = 0.f, o21 = 0.f, o22 = 0.f;
  if (i >= 1 && i <= N - 3) {
    const float ax = ldx<ISBF16>(Xb, (i - 1) * 3 + 0), ay = ldx<ISBF16>(Xb, (i - 1) * 3 + 1), az = ldx<ISBF16>(Xb, (i - 1) * 3 + 2);
    const float cx = ldx<ISBF16>(Xb, (i + 1) * 3 + 0), cy = ldx<ISBF16>(Xb, (i + 1) * 3 + 1), cz = ldx<ISBF16>(Xb, (i + 1) * 3 + 2);
    const float ex = ldx<ISBF16>(Xb, (i + 2) * 3 + 0), ey = ldx<ISBF16>(Xb, (i + 2) * 3 + 1), ez = ldx<ISBF16>(Xb, (i + 2) * 3 + 2);
    float u2x = xi - ax, u2y = yi - ay, u2z = zi - az; norm3(u2x, u2y, u2z);  // U[i-1]
    float u1x = cx - xi, u1y = cy - yi, u1z = cz - zi; norm3(u1x, u1y, u1z);  // U[i]
    float u0x = ex - cx, u0y = ey - cy, u0z = ez - cz; norm3(u0x, u0y, u0z);  // U[i+1]
    float n2x, n2y, n2z; cross3(u2x, u2y, u2z, u1x, u1y, u1z, n2x, n2y, n2z); norm3(n2x, n2y, n2z);
    float n1x, n1y, n1z; cross3(u1x, u1y, u1z, u0x, u0y, u0z, n1x, n1y, n1z); norm3(n1x, n1y, n1z);
    const float dotu = (u1x * u0x + u1y * u0y) + u1z * u0z;
    const float cosA = fminf(fmaxf(-dotu, -1.0f + 1e-6f), 1.0f - 1e-6f);
    const float sinA = __builtin_amdgcn_sqrtf(fmaxf(1.0f - cosA * cosA, 0.0f));
    const float dotn = (n2x * n1x + n2y * n1y) + n2z * n1z;
    const float cosD = fminf(fmaxf(dotn, -1.0f + 1e-6f), 1.0f - 1e-6f);
    const float sinDm = __builtin_amdgcn_sqrtf(fmaxf(1.0f - cosD * cosD, 0.0f));
    const float du2n1 = (u2x * n1x + u2y * n1y) + u2z * n1z;
    const float sg = (du2n1 > 0.f) ? 1.f : ((du2n1 < 0.f) ? -1.f : 0.f);
    ad0 = cosA; ad1 = sinA * cosD; ad2 = sinA * (sg * sinDm);
    float o1x = u2x - u1x, o1y = u2y - u1y, o1z = u2z - u1z; norm3(o1x, o1y, o1z);
    o00 = o1x; o01 = o1y; o02 = o1z;
    o10 = n2x; o11 = n2y; o12 = n2z;
    cross3(o1x, o1y, o1z, n2x, n2y, n2z, o20, o21, o22);
  }

  const int row = b * N + i;

  // ---- Phase 3a: pos_emb, all 64 lanes over 480 contiguous values. ----
  // p = idx & 15 is loop-invariant (64 % 16 == 0): hoist freq and cos/sin pick.
  {
    const size_t base = OFF_POS + (size_t)row * (K * 16);
    const int p = lane & 15;
    const float fr = __expf((float)((p & 7) * 2) * -0.57564627f);
    const bool is_cos = (p < 8);
#pragma unroll
    for (int it = 0; it < 8; ++it) {
      const int idx = it * 64 + lane;
      const int k = (idx >> 4) < K ? (idx >> 4) : (K - 1);
      const int jk = __shfl(sjv, k, 64);     // uniform-active shfl
      const float df = (float)(jk - i);
      const float r = red2pi(df * fr);
      const float v = is_cos ? __cosf(r) : __sinf(r);
      if (idx < K * 16) out[base + idx] = v;
    }
  }

  // ---- Phase 3b: gs_d, all 64 lanes over 450 contiguous values. ----
  {
    const size_t base = OFF_GS + (size_t)row * (K * 15);
#pragma unroll
    for (int it = 0; it < 8; ++it) {
      const int idx = it * 64 + lane;
      const int kq = idx / 15;
      const int k = kq < K ? kq : (K - 1);
      const int m = idx - kq * 15;
      const float d = __shfl(sdv, k, 64);    // uniform-active shfl
      const float mu = (float)(m * (20.0 / 14.0));
      const float q = (d - mu) * 0.75f;
      const float v = __expf(-(q * q));
      if (idx < K * 15) out[base + idx] = v;
    }
  }

  // ---- Phase 3c: E_idx, D_neighbors, O_features on lanes < K; AD on 30..32. ----
  if (lane < K) {
    const size_t rowk = (size_t)row * K + lane;
    const int   j = sjv;
    out[OFF_E  + rowk] = (float)j;
    out[OFF_DN + rowk] = sdv;

    // O_features: normalize(O3 @ (X[j] - X[i])), eps 1e-12; shared rcp scale
    float px, py, pz;
    if constexpr (ISBF16) {
      px = ldx<true>(Xb, j * 3 + 0);
      py = ldx<true>(Xb, j * 3 + 1);
      pz = ldx<true>(Xb, j * 3 + 2);
    } else {
      const F3 p = ((const F3*)Xb)[j];
      px = p.x; py = p.y; pz = p.z;
    }
    const float gx = px - xi, gy = py - yi, gz = pz - zi;
    const float v0 = (o00 * gx + o01 * gy) + o02 * gz;
    const float v1 = (o10 * gx + o11 * gy) + o12 * gz;
    const float v2 = (o20 * gx + o21 * gy) + o22 * gz;
    const float nn = fmaxf(__builtin_amdgcn_sqrtf((v0 * v0 + v1 * v1) + v2 * v2), 1e-12f);
    const float inv = __builtin_amdgcn_rcpf(nn);
    out[OFF_O + rowk * 3 + 0] = v0 * inv;
    out[OFF_O + rowk * 3 + 1] = v1 * inv;
    out[OFF_O + rowk * 3 + 2] = v2 * inv;
  } else if (lane < K + 3) {
    const int c = lane - K;
    const float v = (c == 0) ? ad0 : (c == 1) ? ad1 : ad2;
    out[OFF_AD + (size_t)row * 3 + c] = v;
  }
}

__global__ __launch_bounds__(64 * ROWS_PER_BLK)
void protein_feat_kernel(const void* __restrict__ X,
                         float* __restrict__ out) {
  const int lane = threadIdx.x & 63;
  const int wv   = threadIdx.x >> 6;               // wave id within WG
  const int row  = blockIdx.x * ROWS_PER_BLK + wv; // 0..B*N-1 (independent per wave)
  const int b    = row >> 12;
  const int i    = row & (N - 1);

  // ---- Input-dtype sniff (hedge): even-indexed uint16s are sane bf16 coords
  // iff the buffer is truly bf16; for float32 they are mantissa noise.
  const unsigned short h = ((const unsigned short*)X)[2 * lane];
  const int e = (h >> 7) & 0xFF;
  const bool sane = ((h & 0x7FFF) == 0) || (e >= 115 && e <= 134);
  const unsigned long long bal = __ballot(sane);
  const bool isbf16 = __popcll(bal) >= 40;

  if (isbf16) {
    const void* Xb = (const void*)((const __hip_bfloat16*)X + (size_t)b * N * 3);
    body<true>(Xb, out, b, i, lane);
  } else {
    const void* Xb = (const void*)((const float*)X + (size_t)b * N * 3);
    body<false>(Xb, out, b, i, lane);
  }
}

extern "C" void kernel_launch(void* const* d_in, const int* in_sizes, int n_in,
                              void* d_out, int out_size, void* d_ws, size_t ws_size,
                              hipStream_t stream) {
  const void* X = d_in[0];
  float* out = (float*)d_out;
  (void)in_sizes; (void)n_in; (void)d_ws; (void)ws_size; (void)out_size;
  protein_feat_kernel<<<dim3(B * N / ROWS_PER_BLK), dim3(64 * ROWS_PER_BLK), 0, stream>>>(X, out);
}

// Round 5
// 101.460 us; speedup vs baseline: 1.4371x; 1.0539x over previous
//
#include <hip/hip_runtime.h>
#include <hip/hip_bf16.h>

// Problem constants (fixed by setup_inputs): coords (2, 4096, 3) float32, num_k = 30.
// Outputs: one flat FLOAT32 buffer, reference return order.
// R5 = R4 + single-instruction DPP min reductions (inline asm, ror-based
// schedule, no identity needed; s_nop 1 covers the VALU->DPP 2-wait hazard).
// Everything else identical to R4 (52.2 us, 32 VGPR, 49% occ).
constexpr int B = 2;
constexpr int N = 4096;
constexpr int K = 30;
constexpr int ROWS_PER_BLK = 4;

constexpr size_t OFF_POS = 0;                                   // B*N*K*16
constexpr size_t OFF_AD  = OFF_POS + (size_t)B * N * K * 16;    // B*N*3
constexpr size_t OFF_O   = OFF_AD  + (size_t)B * N * 3;         // B*N*K*3
constexpr size_t OFF_GS  = OFF_O   + (size_t)B * N * K * 3;     // B*N*K*15
constexpr size_t OFF_DN  = OFF_GS  + (size_t)B * N * K * 15;    // B*N*K
constexpr size_t OFF_E   = OFF_DN  + (size_t)B * N * K;         // B*N*K

constexpr float BIGD = 1e30f;               // d/s identity (real d < 300, s < 9e4)
constexpr unsigned int BIGJ = 0xFFFFFFFFu;  // j identity for u32 min

struct F3 { float x, y, z; };               // 12B -> global_load_dwordx3

typedef float v2f __attribute__((ext_vector_type(2)));

template <bool ISBF16>
__device__ __forceinline__ float ldx(const void* __restrict__ X, int idx) {
  if constexpr (ISBF16) {
    return __bfloat162float(((const __hip_bfloat16*)X)[idx]);
  } else {
    return ((const float*)X)[idx];
  }
}

// Selection exactness: np-exact f32 ops, no FMA. The squared sum must use the
// SAME association everywhere: ((dx*dx + dy*dy) + dz*dz), then + 1e-6f.
template <bool ISBF16>
__device__ __forceinline__ float dist_core(float px, float py, float pz,
                                           float xi, float yi, float zi) {
#pragma clang fp contract(off)
  const float dx = px - xi;
  const float dy = py - yi;
  const float dz = pz - zi;
  return sqrtf(((dx * dx + dy * dy) + dz * dz) + 1e-6f);
}

template <bool ISBF16>
__device__ __forceinline__ float distf(const void* __restrict__ Xb, int j,
                                       float xi, float yi, float zi) {
  float px, py, pz;
  if constexpr (ISBF16) {
    px = ldx<true>(Xb, j * 3 + 0);
    py = ldx<true>(Xb, j * 3 + 1);
    pz = ldx<true>(Xb, j * 3 + 2);
  } else {
    const F3 p = ((const F3*)Xb)[j];   // one dwordx3 load
    px = p.x; py = p.y; pz = p.z;
  }
  return dist_core<ISBF16>(px, py, pz, xi, yi, zi);
}

// ---- Fused single-instruction DPP 64-lane min, result read from lane 63. --
// Schedule: row_ror 1/2/4/8 (rotations: every source lane valid, no identity
// needed) -> each lane holds its row-of-16 min; then row_bcast:15 (lane15->
// row1, lane47->row3) and row_bcast:31 (lane31->lanes32..63). Lanes with
// invalid DPP sources simply don't write (bound_ctrl off) -- harmless, only
// lane 63 is read. s_nop 1 between stages: VALU->DPP read needs 2 wait states
// and the compiler cannot see inside the asm blob.
__device__ __forceinline__ float wave_min_f32_bcast(float v) {
  asm("s_nop 1\n\t"
      "v_min_f32 %0, %0, %0 row_ror:1 row_mask:0xf bank_mask:0xf\n\t"
      "s_nop 1\n\t"
      "v_min_f32 %0, %0, %0 row_ror:2 row_mask:0xf bank_mask:0xf\n\t"
      "s_nop 1\n\t"
      "v_min_f32 %0, %0, %0 row_ror:4 row_mask:0xf bank_mask:0xf\n\t"
      "s_nop 1\n\t"
      "v_min_f32 %0, %0, %0 row_ror:8 row_mask:0xf bank_mask:0xf\n\t"
      "s_nop 1\n\t"
      "v_min_f32 %0, %0, %0 row_bcast:15 row_mask:0xf bank_mask:0xf\n\t"
      "s_nop 1\n\t"
      "v_min_f32 %0, %0, %0 row_bcast:31 row_mask:0xf bank_mask:0xf"
      : "+v"(v));
  return __int_as_float(__builtin_amdgcn_readlane(__float_as_int(v), 63));
}
__device__ __forceinline__ unsigned int wave_min_u32_bcast(unsigned int v) {
  asm("s_nop 1\n\t"
      "v_min_u32 %0, %0, %0 row_ror:1 row_mask:0xf bank_mask:0xf\n\t"
      "s_nop 1\n\t"
      "v_min_u32 %0, %0, %0 row_ror:2 row_mask:0xf bank_mask:0xf\n\t"
      "s_nop 1\n\t"
      "v_min_u32 %0, %0, %0 row_ror:4 row_mask:0xf bank_mask:0xf\n\t"
      "s_nop 1\n\t"
      "v_min_u32 %0, %0, %0 row_ror:8 row_mask:0xf bank_mask:0xf\n\t"
      "s_nop 1\n\t"
      "v_min_u32 %0, %0, %0 row_bcast:15 row_mask:0xf bank_mask:0xf\n\t"
      "s_nop 1\n\t"
      "v_min_u32 %0, %0, %0 row_bcast:31 row_mask:0xf bank_mask:0xf"
      : "+v"(v));
  return (unsigned int)__builtin_amdgcn_readlane((int)v, 63);
}

// Lex (d, j) argmin over heads, wave-uniform result. Matches top_k stable order.
__device__ __forceinline__ void lex_argmin(float d0, int j0,
                                           float& dmin, unsigned int& jmin) {
  dmin = wave_min_f32_bcast(d0);
  const unsigned long long tie = __ballot(d0 == dmin);
  if (__popcll(tie) == 1) {                 // wave-uniform branch
    const int wl = __ffsll((unsigned long long)tie) - 1;
    jmin = (unsigned int)__builtin_amdgcn_readlane(j0, wl);
  } else {
    const unsigned int jc = (d0 == dmin) ? (unsigned int)j0 : BIGJ;
    jmin = wave_min_u32_bcast(jc);
  }
}

// range-reduce to |r| <= pi, then native sin/cos (safe domain for v_sin/v_cos)
__device__ __forceinline__ float red2pi(float x) {
  return x - 6.28318530718f * rintf(x * 0.15915494309f);
}

// Feature-path normalize: native sqrt/rcp (1 ulp). inv is a SHARED positive
// scale across x,y,z -> downstream directions, signs, and dot-sign tests are
// unaffected; magnitude off by ~2 ulp (2% output threshold).
__device__ __forceinline__ void norm3(float& x, float& y, float& z) {
  float n = __builtin_amdgcn_sqrtf((x * x + y * y) + z * z);
  n = fmaxf(n, 1e-12f);
  const float inv = __builtin_amdgcn_rcpf(n);
  x *= inv; y *= inv; z *= inv;
}

__device__ __forceinline__ void cross3(float ax, float ay, float az,
                                       float bx, float by, float bz,
                                       float& cx, float& cy, float& cz) {
  cx = ay * bz - az * by;
  cy = az * bx - ax * bz;
  cz = ax * by - ay * bx;
}

// Sorted top-2 insert by full key (fallback rescan path only).
__device__ __forceinline__ void ins2(float d, int j,
                                     float& d0, float& d1, int& j0, int& j1) {
  const bool lt1 = d < d1;
  const float td = lt1 ? d : d1;
  const int   tj = lt1 ? j : j1;
  const bool lt0 = td < d0;
  d1 = lt0 ? d0 : td;  j1 = lt0 ? j0 : tj;
  d0 = lt0 ? td : d0;  j0 = lt0 ? tj : j0;
}

template <bool ISBF16>
__device__ __forceinline__ void body(const void* __restrict__ Xb,
                                     float* __restrict__ out,
                                     int b, int i, int lane) {
  const float xi = ldx<ISBF16>(Xb, i * 3 + 0);
  const float yi = ldx<ISBF16>(Xb, i * 3 + 1);
  const float zi = ldx<ISBF16>(Xb, i * 3 + 2);

  // ---- Phase 1: lane l owns column {j : j % 64 == l}. Select by RAW squared
  // sum ss (no sqrt, no +eps in the loop). Value updates via v_med3 (exact
  // selection ops): s1=med3(ss,s0,s1), s2v=med3(ss,s1_old,s2v), s0=min.
  // Index updates: 3 cndmask off 2 cmps; strict < is j-stable (j ascends).
  float s0 = BIGD, s1 = BIGD, s2v = BIGD;
  int   j0 = 0x7FFFFFFF, j1 = 0x7FFFFFFF;
  if constexpr (!ISBF16) {
    const F3* __restrict__ P = ((const F3*)Xb) + lane;  // pointer-strided
    const v2f xyi = {xi, yi};
#pragma unroll 8
    for (int t = 0; t < 64; ++t) {
      const F3 p = P[t * 64];
      const int j = t * 64 + lane;
      float ss;
      {
#pragma clang fp contract(off)
        const v2f pxy = {p.x, p.y};          // consecutive VGPRs from dwordx3
        const v2f a = pxy - xyi;             // v_pk_add_f32 (sub)
        const v2f m = a * a;                 // v_pk_mul_f32
        const float dz = p.z - zi;
        ss = (m.x + m.y) + dz * dz;          // same assoc as dist_core (pre-eps)
      }
      const bool c0 = ss < s0;
      const bool c1 = ss < s1;
      const float n1 = __builtin_amdgcn_fmed3f(ss, s0, s1);   // OLD s0,s1
      s2v = __builtin_amdgcn_fmed3f(ss, s1, s2v);             // OLD s1
      s0 = fminf(ss, s0);
      j1 = c0 ? j0 : (c1 ? j : j1);                           // OLD j0
      j0 = c0 ? j : j0;
      s1 = n1;
    }
  } else {
#pragma unroll 8
    for (int t = 0; t < 64; ++t) {
      const int j = t * 64 + lane;
      const float px = ldx<true>(Xb, j * 3 + 0);
      const float py = ldx<true>(Xb, j * 3 + 1);
      const float pz = ldx<true>(Xb, j * 3 + 2);
      float ss;
      {
#pragma clang fp contract(off)
        const float dx = px - xi;
        const float dy = py - yi;
        const float dz = pz - zi;
        ss = (dx * dx + dy * dy) + dz * dz;
      }
      const bool c0 = ss < s0;
      const bool c1 = ss < s1;
      const float n1 = __builtin_amdgcn_fmed3f(ss, s0, s1);
      s2v = __builtin_amdgcn_fmed3f(ss, s1, s2v);
      s0 = fminf(ss, s0);
      j1 = c0 ? j0 : (c1 ? j : j1);
      j0 = c0 ? j : j0;
      s1 = n1;
    }
  }

  // ---- Convert to exact d: fold +eps then precise sqrt — bit-identical to
  // distf's final ops. Exactness: d(x)=sqrt((x+eps) rounded) is monotone
  // non-decreasing in x, so {top-2 by ss} == {top-2 by d} as a SET.
  //  * In-cache order: ss0<=ss1 -> d0<=d1; on d0==d1 restore j-ascending.
  //  * If d1 == d2v: an evicted element (ss >= s2v -> d >= d2v) may d-tie the
  //    kept 2nd with smaller j -> exact d-keyed rescan (probability ~0).
  float d0 = sqrtf(s0 + 1e-6f), d1 = sqrtf(s1 + 1e-6f);
  const float d2v = sqrtf(s2v + 1e-6f);
  if (d0 == d1 && j0 > j1) { const int t = j0; j0 = j1; j1 = t; }
  const bool hazard = (__ballot(d1 == d2v) != 0ull);   // wave-uniform
  if (hazard) {
    d0 = BIGD; d1 = BIGD; j0 = 0x7FFFFFFF; j1 = 0x7FFFFFFF;
    for (int t = 0; t < 64; ++t) {
      const int j = t * 64 + lane;
      const float d = distf<ISBF16>(Xb, j, xi, yi, zi);
      ins2(d, j, d0, d1, j0, j1);
    }
  }

  // ---- Phase 2: 30 pops. lex_argmin over heads; winner lane shifts its
  // cache; if it emptied, cooperatively recompute its column (bit-identical
  // distf) with consumed-mask exclusion and refill (~0.65 refills/row).
  unsigned long long exm = 0;   // consumed t's within this lane's own column
  int   sjv = 0;                // lane k (<K): neighbor k's index j
  float sdv = 0.0f;             // lane k (<K): neighbor k's distance d
  for (int k = 0; k < K; ++k) {
    float dmin; unsigned int jmin;
    lex_argmin(d0, j0, dmin, jmin);
    if (lane == k) { sjv = (int)jmin; sdv = dmin; }

    const int w  = (int)(jmin & 63u);   // winning column (wave-uniform)
    const int tw = (int)(jmin >> 6);
    if (lane == w) {            // pop head, mark consumed
      exm |= (1ull << tw);
      d0 = d1; j0 = j1;
      d1 = BIGD; j1 = 0x7FFFFFFF;
    }
    // only the just-popped lane can be empty: scalar check via readlane
    if (__builtin_amdgcn_readlane(__float_as_int(d0), w) == __float_as_int(BIGD)) {
      const unsigned int mlo = (unsigned int)__builtin_amdgcn_readlane((int)(unsigned int)(exm & 0xFFFFFFFFull), w);
      const unsigned int mhi = (unsigned int)__builtin_amdgcn_readlane((int)(unsigned int)(exm >> 32), w);
      const unsigned long long m = ((unsigned long long)mhi << 32) | mlo;
      const int j2 = (lane << 6) | w;      // lane t recomputes column w entry t
      const float d2 = distf<ISBF16>(Xb, j2, xi, yi, zi);
      const float dc = ((m >> lane) & 1ull) ? BIGD : d2;
      float dmin2; unsigned int jmin2;
      lex_argmin(dc, j2, dmin2, jmin2);
      if (lane == w) { d0 = dmin2; j0 = (int)jmin2; }
    }
  }

  // ---- Row-uniform AD features and frame O3 (all lanes redundantly). ----
  // Identities: cos(acos x)=x, sin(acos x)=sqrt(1-x^2) (A in [0,pi]),
  // sin(sg*acos x)=sg*sqrt(1-x^2) -- no acos/sin/cos chains (R3-validated).
  float ad0 = 0.f, ad1 = 0.f, ad2 = 0.f;
  float o00 = 0.f, o01 = 0.f, o02 = 0.f;
  float o10 = 0.f, o11 = 0.f, o12 = 0.f;
  float o20 = 0.f, o21 = 0.f, o22 = 0.f;
  if (i >= 1 && i <= N - 3) {
    const float ax = ldx<ISBF16>(Xb, (i - 1) * 3 + 0), ay = ldx<ISBF16>(Xb, (i - 1) * 3 + 1), az = ldx<ISBF16>(Xb, (i - 1) * 3 + 2);
    const float cx = ldx<ISBF16>(Xb, (i + 1) * 3 + 0), cy = ldx<ISBF16>(Xb, (i + 1) * 3 + 1), cz = ldx<ISBF16>(Xb, (i + 1) * 3 + 2);
    const float ex = ldx<ISBF16>(Xb, (i + 2) * 3 + 0), ey = ldx<ISBF16>(Xb, (i + 2) * 3 + 1), ez = ldx<ISBF16>(Xb, (i + 2) * 3 + 2);
    float u2x = xi - ax, u2y = yi - ay, u2z = zi - az; norm3(u2x, u2y, u2z);  // U[i-1]
    float u1x = cx - xi, u1y = cy - yi, u1z = cz - zi; norm3(u1x, u1y, u1z);  // U[i]
    float u0x = ex - cx, u0y = ey - cy, u0z = ez - cz; norm3(u0x, u0y, u0z);  // U[i+1]
    float n2x, n2y, n2z; cross3(u2x, u2y, u2z, u1x, u1y, u1z, n2x, n2y, n2z); norm3(n2x, n2y, n2z);
    float n1x, n1y, n1z; cross3(u1x, u1y, u1z, u0x, u0y, u0z, n1x, n1y, n1z); norm3(n1x, n1y, n1z);
    const float dotu = (u1x * u0x + u1y * u0y) + u1z * u0z;
    const float cosA = fminf(fmaxf(-dotu, -1.0f + 1e-6f), 1.0f - 1e-6f);
    const float sinA = __builtin_amdgcn_sqrtf(fmaxf(1.0f - cosA * cosA, 0.0f));
    const float dotn = (n2x * n1x + n2y * n1y) + n2z * n1z;
    const float cosD = fminf(fmaxf(dotn, -1.0f + 1e-6f), 1.0f - 1e-6f);
    const float sinDm = __builtin_amdgcn_sqrtf(fmaxf(1.0f - cosD * cosD, 0.0f));
    const float du2n1 = (u2x * n1x + u2y * n1y) + u2z * n1z;
    const float sg = (du2n1 > 0.f) ? 1.f : ((du2n1 < 0.f) ? -1.f : 0.f);
    ad0 = cosA; ad1 = sinA * cosD; ad2 = sinA * (sg * sinDm);
    float o1x = u2x - u1x, o1y = u2y - u1y, o1z = u2z - u1z; norm3(o1x, o1y, o1z);
    o00 = o1x; o01 = o1y; o02 = o1z;
    o10 = n2x; o11 = n2y; o12 = n2z;
    cross3(o1x, o1y, o1z, n2x, n2y, n2z, o20, o21, o22);
  }

  const int row = b * N + i;

  // ---- Phase 3a: pos_emb, all 64 lanes over 480 contiguous values. ----
  // p = idx & 15 is loop-invariant (64 % 16 == 0): hoist freq and cos/sin pick.
  {
    const size_t base = OFF_POS + (size_t)row * (K * 16);
    const int p = lane & 15;
    const float fr = __expf((float)((p & 7) * 2) * -0.57564627f);
    const bool is_cos = (p < 8);
#pragma unroll
    for (int it = 0; it < 8; ++it) {
      const int idx = it * 64 + lane;
      const int k = (idx >> 4) < K ? (idx >> 4) : (K - 1);
      const int jk = __shfl(sjv, k, 64);     // uniform-active shfl
      const float df = (float)(jk - i);
      const float r = red2pi(df * fr);
      const float v = is_cos ? __cosf(r) : __sinf(r);
      if (idx < K * 16) out[base + idx] = v;
    }
  }

  // ---- Phase 3b: gs_d, all 64 lanes over 450 contiguous values. ----
  {
    const size_t base = OFF_GS + (size_t)row * (K * 15);
#pragma unroll
    for (int it = 0; it < 8; ++it) {
      const int idx = it * 64 + lane;
      const int kq = idx / 15;
      const int k = kq < K ? kq : (K - 1);
      const int m = idx - kq * 15;
      const float d = __shfl(sdv, k, 64);    // uniform-active shfl
      const float mu = (float)(m * (20.0 / 14.0));
      const float q = (d - mu) * 0.75f;
      const float v = __expf(-(q * q));
      if (idx < K * 15) out[base + idx] = v;
    }
  }

  // ---- Phase 3c: E_idx, D_neighbors, O_features on lanes < K; AD on 30..32. ----
  if (lane < K) {
    const size_t rowk = (size_t)row * K + lane;
    const int   j = sjv;
    out[OFF_E  + rowk] = (float)j;
    out[OFF_DN + rowk] = sdv;

    // O_features: normalize(O3 @ (X[j] - X[i])), eps 1e-12; shared rcp scale
    float px, py, pz;
    if constexpr (ISBF16) {
      px = ldx<true>(Xb, j * 3 + 0);
      py = ldx<true>(Xb, j * 3 + 1);
      pz = ldx<true>(Xb, j * 3 + 2);
    } else {
      const F3 p = ((const F3*)Xb)[j];
      px = p.x; py = p.y; pz = p.z;
    }
    const float gx = px - xi, gy = py - yi, gz = pz - zi;
    const float v0 = (o00 * gx + o01 * gy) + o02 * gz;
    const float v1 = (o10 * gx + o11 * gy) + o12 * gz;
    const float v2 = (o20 * gx + o21 * gy) + o22 * gz;
    const float nn = fmaxf(__builtin_amdgcn_sqrtf((v0 * v0 + v1 * v1) + v2 * v2), 1e-12f);
    const float inv = __builtin_amdgcn_rcpf(nn);
    out[OFF_O + rowk * 3 + 0] = v0 * inv;
    out[OFF_O + rowk * 3 + 1] = v1 * inv;
    out[OFF_O + rowk * 3 + 2] = v2 * inv;
  } else if (lane < K + 3) {
    const int c = lane - K;
    const float v = (c == 0) ? ad0 : (c == 1) ? ad1 : ad2;
    out[OFF_AD + (size_t)row * 3 + c] = v;
  }
}

__global__ __launch_bounds__(64 * ROWS_PER_BLK)
void protein_feat_kernel(const void* __restrict__ X,
                         float* __restrict__ out) {
  const int lane = threadIdx.x & 63;
  const int wv   = threadIdx.x >> 6;               // wave id within WG
  const int row  = blockIdx.x * ROWS_PER_BLK + wv; // 0..B*N-1 (independent per wave)
  const int b    = row >> 12;
  const int i    = row & (N - 1);

  // ---- Input-dtype sniff (hedge): even-indexed uint16s are sane bf16 coords
  // iff the buffer is truly bf16; for float32 they are mantissa noise.
  const unsigned short h = ((const unsigned short*)X)[2 * lane];
  const int e = (h >> 7) & 0xFF;
  const bool sane = ((h & 0x7FFF) == 0) || (e >= 115 && e <= 134);
  const unsigned long long bal = __ballot(sane);
  const bool isbf16 = __popcll(bal) >= 40;

  if (isbf16) {
    const void* Xb = (const void*)((const __hip_bfloat16*)X + (size_t)b * N * 3);
    body<true>(Xb, out, b, i, lane);
  } else {
    const void* Xb = (const void*)((const float*)X + (size_t)b * N * 3);
    body<false>(Xb, out, b, i, lane);
  }
}

extern "C" void kernel_launch(void* const* d_in, const int* in_sizes, int n_in,
                              void* d_out, int out_size, void* d_ws, size_t ws_size,
                              hipStream_t stream) {
  const void* X = d_in[0];
  float* out = (float*)d_out;
  (void)in_sizes; (void)n_in; (void)d_ws; (void)ws_size; (void)out_size;
  protein_feat_kernel<<<dim3(B * N / ROWS_PER_BLK), dim3(64 * ROWS_PER_BLK), 0, stream>>>(X, out);
}

// Round 8
// 100.066 us; speedup vs baseline: 1.4571x; 1.0139x over previous
//
#include <hip/hip_runtime.h>
#include <hip/hip_bf16.h>

// Problem constants (fixed by setup_inputs): coords (2, 4096, 3) float32, num_k = 30.
// Outputs: one flat FLOAT32 buffer, reference return order.
// R8 = R5 (48.1 us, 32 VGPR, 50% occ) + the compilable subset of R6:
//   - pop-loop #pragma unroll 5 (exact divisor of 30, no epilogue)
//   - __builtin_expect on rare tie/empty/hazard branches
//   - pos_emb cos(r)=sin(r+pi/2) single-transcendental (red2pi unchanged)
// R6/R7 lesson: __builtin_amdgcn_writelane does NOT exist in this ROCm clang
// (readlane does). Result capture stays in R5's lane==k / lane==w form.
constexpr int B = 2;
constexpr int N = 4096;
constexpr int K = 30;
constexpr int ROWS_PER_BLK = 4;

constexpr size_t OFF_POS = 0;                                   // B*N*K*16
constexpr size_t OFF_AD  = OFF_POS + (size_t)B * N * K * 16;    // B*N*3
constexpr size_t OFF_O   = OFF_AD  + (size_t)B * N * 3;         // B*N*K*3
constexpr size_t OFF_GS  = OFF_O   + (size_t)B * N * K * 3;     // B*N*K*15
constexpr size_t OFF_DN  = OFF_GS  + (size_t)B * N * K * 15;    // B*N*K
constexpr size_t OFF_E   = OFF_DN  + (size_t)B * N * K;         // B*N*K

constexpr float BIGD = 1e30f;               // d/s identity (real d < 300, s < 9e4)
constexpr unsigned int BIGJ = 0xFFFFFFFFu;  // j identity for u32 min

struct F3 { float x, y, z; };               // 12B -> global_load_dwordx3

typedef float v2f __attribute__((ext_vector_type(2)));

template <bool ISBF16>
__device__ __forceinline__ float ldx(const void* __restrict__ X, int idx) {
  if constexpr (ISBF16) {
    return __bfloat162float(((const __hip_bfloat16*)X)[idx]);
  } else {
    return ((const float*)X)[idx];
  }
}

// Selection exactness: np-exact f32 ops, no FMA. The squared sum must use the
// SAME association everywhere: ((dx*dx + dy*dy) + dz*dz), then + 1e-6f.
template <bool ISBF16>
__device__ __forceinline__ float dist_core(float px, float py, float pz,
                                           float xi, float yi, float zi) {
#pragma clang fp contract(off)
  const float dx = px - xi;
  const float dy = py - yi;
  const float dz = pz - zi;
  return sqrtf(((dx * dx + dy * dy) + dz * dz) + 1e-6f);
}

template <bool ISBF16>
__device__ __forceinline__ float distf(const void* __restrict__ Xb, int j,
                                       float xi, float yi, float zi) {
  float px, py, pz;
  if constexpr (ISBF16) {
    px = ldx<true>(Xb, j * 3 + 0);
    py = ldx<true>(Xb, j * 3 + 1);
    pz = ldx<true>(Xb, j * 3 + 2);
  } else {
    const F3 p = ((const F3*)Xb)[j];   // one dwordx3 load
    px = p.x; py = p.y; pz = p.z;
  }
  return dist_core<ISBF16>(px, py, pz, xi, yi, zi);
}

// ---- Fused single-instruction DPP 64-lane min, result read from lane 63. --
// Schedule: row_ror 1/2/4/8 (rotations: every source lane valid, no identity
// needed) -> each lane holds its row-of-16 min; then row_bcast:15 and
// row_bcast:31. Invalid-source lanes simply don't write (bound_ctrl off) --
// harmless, only lane 63 is read. s_nop 1 between stages: VALU->DPP read
// needs 2 wait states and the compiler cannot see inside the asm blob.
__device__ __forceinline__ float wave_min_f32_bcast(float v) {
  asm("s_nop 1\n\t"
      "v_min_f32 %0, %0, %0 row_ror:1 row_mask:0xf bank_mask:0xf\n\t"
      "s_nop 1\n\t"
      "v_min_f32 %0, %0, %0 row_ror:2 row_mask:0xf bank_mask:0xf\n\t"
      "s_nop 1\n\t"
      "v_min_f32 %0, %0, %0 row_ror:4 row_mask:0xf bank_mask:0xf\n\t"
      "s_nop 1\n\t"
      "v_min_f32 %0, %0, %0 row_ror:8 row_mask:0xf bank_mask:0xf\n\t"
      "s_nop 1\n\t"
      "v_min_f32 %0, %0, %0 row_bcast:15 row_mask:0xf bank_mask:0xf\n\t"
      "s_nop 1\n\t"
      "v_min_f32 %0, %0, %0 row_bcast:31 row_mask:0xf bank_mask:0xf"
      : "+v"(v));
  return __int_as_float(__builtin_amdgcn_readlane(__float_as_int(v), 63));
}
__device__ __forceinline__ unsigned int wave_min_u32_bcast(unsigned int v) {
  asm("s_nop 1\n\t"
      "v_min_u32 %0, %0, %0 row_ror:1 row_mask:0xf bank_mask:0xf\n\t"
      "s_nop 1\n\t"
      "v_min_u32 %0, %0, %0 row_ror:2 row_mask:0xf bank_mask:0xf\n\t"
      "s_nop 1\n\t"
      "v_min_u32 %0, %0, %0 row_ror:4 row_mask:0xf bank_mask:0xf\n\t"
      "s_nop 1\n\t"
      "v_min_u32 %0, %0, %0 row_ror:8 row_mask:0xf bank_mask:0xf\n\t"
      "s_nop 1\n\t"
      "v_min_u32 %0, %0, %0 row_bcast:15 row_mask:0xf bank_mask:0xf\n\t"
      "s_nop 1\n\t"
      "v_min_u32 %0, %0, %0 row_bcast:31 row_mask:0xf bank_mask:0xf"
      : "+v"(v));
  return (unsigned int)__builtin_amdgcn_readlane((int)v, 63);
}

// Lex (d, j) argmin over heads, wave-uniform result. Matches top_k stable order.
__device__ __forceinline__ void lex_argmin(float d0, int j0,
                                           float& dmin, unsigned int& jmin) {
  dmin = wave_min_f32_bcast(d0);
  const unsigned long long tie = __ballot(d0 == dmin);
  if (__builtin_expect(__popcll(tie) == 1, 1)) {   // wave-uniform fast path
    const int wl = __ffsll((unsigned long long)tie) - 1;
    jmin = (unsigned int)__builtin_amdgcn_readlane(j0, wl);
  } else {
    const unsigned int jc = (d0 == dmin) ? (unsigned int)j0 : BIGJ;
    jmin = wave_min_u32_bcast(jc);
  }
}

// range-reduce to |r| <= pi, then native sin/cos (safe domain for v_sin/v_cos)
__device__ __forceinline__ float red2pi(float x) {
  return x - 6.28318530718f * rintf(x * 0.15915494309f);
}

// Feature-path normalize: native sqrt/rcp (1 ulp). inv is a SHARED positive
// scale across x,y,z -> downstream directions, signs, and dot-sign tests are
// unaffected; magnitude off by ~2 ulp (2% output threshold).
__device__ __forceinline__ void norm3(float& x, float& y, float& z) {
  float n = __builtin_amdgcn_sqrtf((x * x + y * y) + z * z);
  n = fmaxf(n, 1e-12f);
  const float inv = __builtin_amdgcn_rcpf(n);
  x *= inv; y *= inv; z *= inv;
}

__device__ __forceinline__ void cross3(float ax, float ay, float az,
                                       float bx, float by, float bz,
                                       float& cx, float& cy, float& cz) {
  cx = ay * bz - az * by;
  cy = az * bx - ax * bz;
  cz = ax * by - ay * bx;
}

// Sorted top-2 insert by full key (fallback rescan path only).
__device__ __forceinline__ void ins2(float d, int j,
                                     float& d0, float& d1, int& j0, int& j1) {
  const bool lt1 = d < d1;
  const float td = lt1 ? d : d1;
  const int   tj = lt1 ? j : j1;
  const bool lt0 = td < d0;
  d1 = lt0 ? d0 : td;  j1 = lt0 ? j0 : tj;
  d0 = lt0 ? td : d0;  j0 = lt0 ? tj : j0;
}

template <bool ISBF16>
__device__ __forceinline__ void body(const void* __restrict__ Xb,
                                     float* __restrict__ out,
                                     int b, int i, int lane) {
  const float xi = ldx<ISBF16>(Xb, i * 3 + 0);
  const float yi = ldx<ISBF16>(Xb, i * 3 + 1);
  const float zi = ldx<ISBF16>(Xb, i * 3 + 2);

  // ---- Phase 1: lane l owns column {j : j % 64 == l}. Select by RAW squared
  // sum ss (no sqrt, no +eps in the loop). Value updates via v_med3 (exact
  // selection ops): s1=med3(ss,s0,s1), s2v=med3(ss,s1_old,s2v), s0=min.
  // Index updates: 3 cndmask off 2 cmps; strict < is j-stable (j ascends).
  float s0 = BIGD, s1 = BIGD, s2v = BIGD;
  int   j0 = 0x7FFFFFFF, j1 = 0x7FFFFFFF;
  if constexpr (!ISBF16) {
    const F3* __restrict__ P = ((const F3*)Xb) + lane;  // pointer-strided
    const v2f xyi = {xi, yi};
#pragma unroll 8
    for (int t = 0; t < 64; ++t) {
      const F3 p = P[t * 64];
      const int j = t * 64 + lane;
      float ss;
      {
#pragma clang fp contract(off)
        const v2f pxy = {p.x, p.y};          // consecutive VGPRs from dwordx3
        const v2f a = pxy - xyi;             // v_pk_add_f32 (sub)
        const v2f m = a * a;                 // v_pk_mul_f32
        const float dz = p.z - zi;
        ss = (m.x + m.y) + dz * dz;          // same assoc as dist_core (pre-eps)
      }
      const bool c0 = ss < s0;
      const bool c1 = ss < s1;
      const float n1 = __builtin_amdgcn_fmed3f(ss, s0, s1);   // OLD s0,s1
      s2v = __builtin_amdgcn_fmed3f(ss, s1, s2v);             // OLD s1
      s0 = fminf(ss, s0);
      j1 = c0 ? j0 : (c1 ? j : j1);                           // OLD j0
      j0 = c0 ? j : j0;
      s1 = n1;
    }
  } else {
#pragma unroll 8
    for (int t = 0; t < 64; ++t) {
      const int j = t * 64 + lane;
      const float px = ldx<true>(Xb, j * 3 + 0);
      const float py = ldx<true>(Xb, j * 3 + 1);
      const float pz = ldx<true>(Xb, j * 3 + 2);
      float ss;
      {
#pragma clang fp contract(off)
        const float dx = px - xi;
        const float dy = py - yi;
        const float dz = pz - zi;
        ss = (dx * dx + dy * dy) + dz * dz;
      }
      const bool c0 = ss < s0;
      const bool c1 = ss < s1;
      const float n1 = __builtin_amdgcn_fmed3f(ss, s0, s1);
      s2v = __builtin_amdgcn_fmed3f(ss, s1, s2v);
      s0 = fminf(ss, s0);
      j1 = c0 ? j0 : (c1 ? j : j1);
      j0 = c0 ? j : j0;
      s1 = n1;
    }
  }

  // ---- Convert to exact d: fold +eps then precise sqrt — bit-identical to
  // distf's final ops. Exactness: d(x)=sqrt((x+eps) rounded) is monotone
  // non-decreasing in x, so {top-2 by ss} == {top-2 by d} as a SET.
  //  * In-cache order: ss0<=ss1 -> d0<=d1; on d0==d1 restore j-ascending.
  //  * If d1 == d2v: an evicted element (ss >= s2v -> d >= d2v) may d-tie the
  //    kept 2nd with smaller j -> exact d-keyed rescan (probability ~0).
  float d0 = sqrtf(s0 + 1e-6f), d1 = sqrtf(s1 + 1e-6f);
  const float d2v = sqrtf(s2v + 1e-6f);
  if (d0 == d1 && j0 > j1) { const int t = j0; j0 = j1; j1 = t; }
  const bool hazard = (__ballot(d1 == d2v) != 0ull);   // wave-uniform
  if (__builtin_expect(hazard, 0)) {
    d0 = BIGD; d1 = BIGD; j0 = 0x7FFFFFFF; j1 = 0x7FFFFFFF;
    for (int t = 0; t < 64; ++t) {
      const int j = t * 64 + lane;
      const float d = distf<ISBF16>(Xb, j, xi, yi, zi);
      ins2(d, j, d0, d1, j0, j1);
    }
  }

  // ---- Phase 2: 30 pops. lex_argmin over heads; winner lane shifts its
  // cache; if it emptied, cooperatively recompute its column (bit-identical
  // distf) with consumed-mask exclusion and refill (~0.65 refills/row).
  unsigned long long exm = 0;   // consumed t's within this lane's own column
  int   sjv = 0;                // lane k (<K): neighbor k's index j
  float sdv = 0.0f;             // lane k (<K): neighbor k's distance d
#pragma unroll 5
  for (int k = 0; k < K; ++k) {
    float dmin; unsigned int jmin;
    lex_argmin(d0, j0, dmin, jmin);
    if (lane == k) { sjv = (int)jmin; sdv = dmin; }

    const int w  = (int)(jmin & 63u);   // winning column (wave-uniform)
    const int tw = (int)(jmin >> 6);
    if (lane == w) {            // pop head, mark consumed
      exm |= (1ull << tw);
      d0 = d1; j0 = j1;
      d1 = BIGD; j1 = 0x7FFFFFFF;
    }
    // only the just-popped lane can be empty: scalar check via readlane
    if (__builtin_expect(
            __builtin_amdgcn_readlane(__float_as_int(d0), w) ==
                __float_as_int(BIGD), 0)) {
      const unsigned int mlo = (unsigned int)__builtin_amdgcn_readlane((int)(unsigned int)(exm & 0xFFFFFFFFull), w);
      const unsigned int mhi = (unsigned int)__builtin_amdgcn_readlane((int)(unsigned int)(exm >> 32), w);
      const unsigned long long m = ((unsigned long long)mhi << 32) | mlo;
      const int j2 = (lane << 6) | w;      // lane t recomputes column w entry t
      const float d2 = distf<ISBF16>(Xb, j2, xi, yi, zi);
      const float dc = ((m >> lane) & 1ull) ? BIGD : d2;
      float dmin2; unsigned int jmin2;
      lex_argmin(dc, j2, dmin2, jmin2);
      if (lane == w) { d0 = dmin2; j0 = (int)jmin2; }
    }
  }

  // ---- Row-uniform AD features and frame O3 (all lanes redundantly). ----
  // Identities: cos(acos x)=x, sin(acos x)=sqrt(1-x^2) (A in [0,pi]),
  // sin(sg*acos x)=sg*sqrt(1-x^2) -- no acos/sin/cos chains (R3-validated).
  float ad0 = 0.f, ad1 = 0.f, ad2 = 0.f;
  float o00 = 0.f, o01 = 0.f, o02 = 0.f;
  float o10 = 0.f, o11 = 0.f, o12 = 0.f;
  float o20 = 0.f, o21 = 0.f, o22 = 0.f;
  if (i >= 1 && i <= N - 3) {
    const float ax = ldx<ISBF16>(Xb, (i - 1) * 3 + 0), ay = ldx<ISBF16>(Xb, (i - 1) * 3 + 1), az = ldx<ISBF16>(Xb, (i - 1) * 3 + 2);
    const float cx = ldx<ISBF16>(Xb, (i + 1) * 3 + 0), cy = ldx<ISBF16>(Xb, (i + 1) * 3 + 1), cz = ldx<ISBF16>(Xb, (i + 1) * 3 + 2);
    const float ex = ldx<ISBF16>(Xb, (i + 2) * 3 + 0), ey = ldx<ISBF16>(Xb, (i + 2) * 3 + 1), ez = ldx<ISBF16>(Xb, (i + 2) * 3 + 2);
    float u2x = xi - ax, u2y = yi - ay, u2z = zi - az; norm3(u2x, u2y, u2z);  // U[i-1]
    float u1x = cx - xi, u1y = cy - yi, u1z = cz - zi; norm3(u1x, u1y, u1z);  // U[i]
    float u0x = ex - cx, u0y = ey - cy, u0z = ez - cz; norm3(u0x, u0y, u0z);  // U[i+1]
    float n2x, n2y, n2z; cross3(u2x, u2y, u2z, u1x, u1y, u1z, n2x, n2y, n2z); norm3(n2x, n2y, n2z);
    float n1x, n1y, n1z; cross3(u1x, u1y, u1z, u0x, u0y, u0z, n1x, n1y, n1z); norm3(n1x, n1y, n1z);
    const float dotu = (u1x * u0x + u1y * u0y) + u1z * u0z;
    const float cosA = fminf(fmaxf(-dotu, -1.0f + 1e-6f), 1.0f - 1e-6f);
    const float sinA = __builtin_amdgcn_sqrtf(fmaxf(1.0f - cosA * cosA, 0.0f));
    const float dotn = (n2x * n1x + n2y * n1y) + n2z * n1z;
    const float cosD = fminf(fmaxf(dotn, -1.0f + 1e-6f), 1.0f - 1e-6f);
    const float sinDm = __builtin_amdgcn_sqrtf(fmaxf(1.0f - cosD * cosD, 0.0f));
    const float du2n1 = (u2x * n1x + u2y * n1y) + u2z * n1z;
    const float sg = (du2n1 > 0.f) ? 1.f : ((du2n1 < 0.f) ? -1.f : 0.f);
    ad0 = cosA; ad1 = sinA * cosD; ad2 = sinA * (sg * sinDm);
    float o1x = u2x - u1x, o1y = u2y - u1y, o1z = u2z - u1z; norm3(o1x, o1y, o1z);
    o00 = o1x; o01 = o1y; o02 = o1z;
    o10 = n2x; o11 = n2y; o12 = n2z;
    cross3(o1x, o1y, o1z, n2x, n2y, n2z, o20, o21, o22);
  }

  const int row = b * N + i;

  // ---- Phase 3a: pos_emb, all 64 lanes over 480 contiguous values. ----
  // p = idx & 15 is loop-invariant (64 % 16 == 0): hoist freq and the
  // cos-vs-sin choice as a +pi/2 phase shift (cos(r) = sin(r + pi/2); the
  // f32 rounding of pi/2 contributes <= 5e-8 -- red2pi path unchanged).
  {
    const size_t base = OFF_POS + (size_t)row * (K * 16);
    const int p = lane & 15;
    const float fr = __expf((float)((p & 7) * 2) * -0.57564627f);
    const float qsh = (p < 8) ? 1.57079632679f : 0.0f;
#pragma unroll
    for (int it = 0; it < 8; ++it) {
      const int idx = it * 64 + lane;
      const int k = (idx >> 4) < K ? (idx >> 4) : (K - 1);
      const int jk = __shfl(sjv, k, 64);     // uniform-active shfl
      const float df = (float)(jk - i);
      const float r = red2pi(df * fr);       // |r| <= pi
      const float v = __sinf(r + qsh);       // r+qsh in [-pi, 3pi/2]: safe
      if (idx < K * 16) out[base + idx] = v;
    }
  }

  // ---- Phase 3b: gs_d, all 64 lanes over 450 contiguous values. ----
  {
    const size_t base = OFF_GS + (size_t)row * (K * 15);
#pragma unroll
    for (int it = 0; it < 8; ++it) {
      const int idx = it * 64 + lane;
      const int kq = idx / 15;
      const int k = kq < K ? kq : (K - 1);
      const int m = idx - kq * 15;
      const float d = __shfl(sdv, k, 64);    // uniform-active shfl
      const float mu = (float)(m * (20.0 / 14.0));
      const float q = (d - mu) * 0.75f;
      const float v = __expf(-(q * q));
      if (idx < K * 15) out[base + idx] = v;
    }
  }

  // ---- Phase 3c: E_idx, D_neighbors, O_features on lanes < K; AD on 30..32. ----
  if (lane < K) {
    const size_t rowk = (size_t)row * K + lane;
    const int   j = sjv;
    out[OFF_E  + rowk] = (float)j;
    out[OFF_DN + rowk] = sdv;

    // O_features: normalize(O3 @ (X[j] - X[i])), eps 1e-12; shared rcp scale
    float px, py, pz;
    if constexpr (ISBF16) {
      px = ldx<true>(Xb, j * 3 + 0);
      py = ldx<true>(Xb, j * 3 + 1);
      pz = ldx<true>(Xb, j * 3 + 2);
    } else {
      const F3 p = ((const F3*)Xb)[j];
      px = p.x; py = p.y; pz = p.z;
    }
    const float gx = px - xi, gy = py - yi, gz = pz - zi;
    const float v0 = (o00 * gx + o01 * gy) + o02 * gz;
    const float v1 = (o10 * gx + o11 * gy) + o12 * gz;
    const float v2 = (o20 * gx + o21 * gy) + o22 * gz;
    const float nn = fmaxf(__builtin_amdgcn_sqrtf((v0 * v0 + v1 * v1) + v2 * v2), 1e-12f);
    const float inv = __builtin_amdgcn_rcpf(nn);
    out[OFF_O + rowk * 3 + 0] = v0 * inv;
    out[OFF_O + rowk * 3 + 1] = v1 * inv;
    out[OFF_O + rowk * 3 + 2] = v2 * inv;
  } else if (lane < K + 3) {
    const int c = lane - K;
    const float v = (c == 0) ? ad0 : (c == 1) ? ad1 : ad2;
    out[OFF_AD + (size_t)row * 3 + c] = v;
  }
}

__global__ __launch_bounds__(64 * ROWS_PER_BLK)
void protein_feat_kernel(const void* __restrict__ X,
                         float* __restrict__ out) {
  const int lane = threadIdx.x & 63;
  const int wv   = threadIdx.x >> 6;               // wave id within WG
  const int row  = blockIdx.x * ROWS_PER_BLK + wv; // 0..B*N-1 (independent per wave)
  const int b    = row >> 12;
  const int i    = row & (N - 1);

  // ---- Input-dtype sniff (hedge): even-indexed uint16s are sane bf16 coords
  // iff the buffer is truly bf16; for float32 they are mantissa noise.
  const unsigned short h = ((const unsigned short*)X)[2 * lane];
  const int e = (h >> 7) & 0xFF;
  const bool sane = ((h & 0x7FFF) == 0) || (e >= 115 && e <= 134);
  const unsigned long long bal = __ballot(sane);
  const bool isbf16 = __popcll(bal) >= 40;

  if (isbf16) {
    const void* Xb = (const void*)((const __hip_bfloat16*)X + (size_t)b * N * 3);
    body<true>(Xb, out, b, i, lane);
  } else {
    const void* Xb = (const void*)((const float*)X + (size_t)b * N * 3);
    body<false>(Xb, out, b, i, lane);
  }
}

extern "C" void kernel_launch(void* const* d_in, const int* in_sizes, int n_in,
                              void* d_out, int out_size, void* d_ws, size_t ws_size,
                              hipStream_t stream) {
  const void* X = d_in[0];
  float* out = (float*)d_out;
  (void)in_sizes; (void)n_in; (void)d_ws; (void)ws_size; (void)out_size;
  protein_feat_kernel<<<dim3(B * N / ROWS_PER_BLK), dim3(64 * ROWS_PER_BLK), 0, stream>>>(X, out);
}